// Round 7
// baseline (2061.979 us; speedup 1.0000x reference)
//
#include <hip/hip_runtime.h>
#include <hip/hip_bf16.h>

typedef _Float16 f16x8 __attribute__((ext_vector_type(8)));
typedef _Float16 f16x4 __attribute__((ext_vector_type(4)));
typedef float f32x4 __attribute__((ext_vector_type(4)));

#define BN_S 0.99999500003749975f  // 1/sqrt(1+1e-5)

__device__ inline f16x8 f16x8_zero() {
  f16x8 v = {(_Float16)0.f, (_Float16)0.f, (_Float16)0.f, (_Float16)0.f,
             (_Float16)0.f, (_Float16)0.f, (_Float16)0.f, (_Float16)0.f};
  return v;
}

__device__ __forceinline__ void load_lds16(const _Float16* g, _Float16* l) {
  __builtin_amdgcn_global_load_lds(
      (const __attribute__((address_space(1))) void*)g,
      (__attribute__((address_space(3))) void*)l, 16, 0, 0);
}

__global__ void zero_out_k(float* __restrict__ out, int n) {
  const int idx = blockIdx.x * 256 + threadIdx.x;
  if (idx < n) out[idx] = 0.f;
}

// zero n16 16-byte blocks
__global__ void zero16_k(_Float16* __restrict__ p, int n16) {
  const int idx = blockIdx.x * 256 + threadIdx.x;
  if (idx < n16) ((f16x8*)p)[idx] = f16x8_zero();
}

// ---------------------------------------------------------------------------
// Weight transform: OIHW fp32 -> [25][O][C] fp16, pre-scaled by g*BN_S.
// ---------------------------------------------------------------------------
__global__ void wtrans16(const float* __restrict__ src, _Float16* __restrict__ dst,
                         const float* __restrict__ g, int O, int C, int total) {
  const int idx = blockIdx.x * 256 + threadIdx.x;  // (t, o, c)
  if (idx >= total) return;
  const int OC = O * C;
  const int t = idx / OC;
  const int rem = idx - t * OC;
  const int o = rem / C;
  const int c = rem - o * C;
  dst[idx] = (_Float16)(src[(size_t)(o * C + c) * 25 + t] * g[o] * BN_S);
}

// conv8 weights: OIHW fp32 (O=3,C=384) -> [48 chunks][25 taps][3][8] fp16.
__global__ void wtrans8(const float* __restrict__ src, _Float16* __restrict__ dst,
                        const float* __restrict__ g) {
  const int idx = blockIdx.x * 256 + threadIdx.x;
  if (idx >= 28800) return;
  const int c = idx / 600;
  const int r = idx - c * 600;
  const int tap = r / 24;
  const int q = r - tap * 24;
  const int o = q >> 3, j = q & 7;
  const int cin = (c < 16) ? (c * 8 + j) : (128 + (c - 16) * 8 + j);
  dst[idx] = (_Float16)(src[((size_t)o * 384 + cin) * 25 + tap] * g[o] * BN_S);
}

// ---------------------------------------------------------------------------
// Implicit-GEMM 5x5 conv + BN + ReLU.  Cin%32==0, Cout%BM==0, pixels%BN==0.
// in: padded NHWC fp16 (2-px zero halo), wt: [25][Cout][Cin] fp16 prescaled.
// Block tile BM(cout) x BN(px); 4 waves 2x2; BK=32.
// 4-buffer LDS rotation, 2-deep prefetch via global_load_lds(16B), counted
// vmcnt (T3/T4: never drain to 0 in steady state) + raw s_barrier.
// XOR-swizzled LDS: halfword(row,chunk) = row*32 + (chunk^((row>>1)&3))*8
// ---------------------------------------------------------------------------
template <int MF, int NF>
__global__ __launch_bounds__(256) void conv_gemm(
    const _Float16* __restrict__ in, const _Float16* __restrict__ wt,
    const float* __restrict__ gg, const float* __restrict__ bbv,
    const float* __restrict__ ev, _Float16* __restrict__ out,
    int Cin, int Cout, int lw, int lh,
    int inS, int Wpi, int bsi, int ibase,
    int outS, int outOff, int Wpo, int bso, int obase) {
  constexpr int BM = MF * 32;
  constexpr int BN = NF * 32;
  constexpr int LPS = ((BM == 128) ? 2 : 1) + ((BN == 128) ? 2 : 1);  // loads/thread/stage
  __shared__ _Float16 sA[4][BM * 32];
  __shared__ _Float16 sB[4][BN * 32];

  const int tid = threadIdx.x;
  const int lane = tid & 63;
  const int wid = tid >> 6;
  const int wm = wid >> 1, wn = wid & 1;
  const int lr = lane >> 4, lc = lane & 15;
  const int n0 = blockIdx.x * BN;
  const int m0 = blockIdx.y * BM;
  const int H = 1 << lh, W = 1 << lw;
  const int nkb = Cin >> 5;

  // staging identity: linear g = issue*256 + tid; row=g>>2, slot=g&3
  const int r0 = tid >> 2;
  const int chunk = (tid & 3) ^ ((r0 >> 1) & 3);  // same for row r0+64

  const _Float16* a0 = wt + (size_t)(m0 + r0) * Cin + (chunk << 3);
  const _Float16* a1 = a0 + ((size_t)Cin << 6);  // used only if BM==128
  const int t0off = -2 * Wpi - 2;  // tap (dy=0,dx=0)
  const _Float16 *b0, *b1 = nullptr;
  {
    int n = n0 + r0;
    int pix0 = (n >> (lw + lh)) * bsi + ((n >> lw) & (H - 1)) * Wpi + (n & (W - 1)) + ibase;
    b0 = in + (size_t)(pix0 + t0off) * inS + (chunk << 3);
    if constexpr (BN == 128) {
      n = n0 + r0 + 64;
      int pix1 = (n >> (lw + lh)) * bsi + ((n >> lw) & (H - 1)) * Wpi + (n & (W - 1)) + ibase;
      b1 = in + (size_t)(pix1 + t0off) * inS + (chunk << 3);
    }
  }

  // ds_read fragment swizzle (halfwords)
  const int swz = (lr ^ ((lc >> 1) & 3)) << 3;

  f32x4 acc[MF][NF];
  const f32x4 vz = {0.f, 0.f, 0.f, 0.f};
#pragma unroll
  for (int i = 0; i < MF; ++i)
#pragma unroll
    for (int j = 0; j < NF; ++j) acc[i][j] = vz;

  const int nt = 25 * nkb;
  int kb = 0, dx = 0;
  const size_t a_tap = (size_t)Cout * Cin - ((size_t)nkb << 5);
  const int woff = wid << 9;  // wave LDS base (halfwords, 1KB per wave-issue)

  // advance staging pointers by one K-step
  auto advance = [&]() {
    a0 += 32; b0 += 32;
    if constexpr (BM == 128) a1 += 32;
    if constexpr (BN == 128) b1 += 32;
    if (++kb == nkb) {
      kb = 0;
      a0 += a_tap;
      if constexpr (BM == 128) a1 += a_tap;
      int pd;
      if (++dx == 5) { dx = 0; pd = Wpi - 4; } else pd = 1;
      const ptrdiff_t bd = (ptrdiff_t)pd * inS - ((ptrdiff_t)nkb << 5);
      b0 += bd;
      if constexpr (BN == 128) b1 += bd;
    }
  };
  auto stage = [&](int buf) {
    _Float16* sa = sA[buf] + woff;
    _Float16* sb = sB[buf] + woff;
    load_lds16(a0, sa);
    if constexpr (BM == 128) load_lds16(a1, sa + 2048);
    load_lds16(b0, sb);
    if constexpr (BN == 128) load_lds16(b1, sb + 2048);
  };

  // prologue: stage steps 0 and 1
  stage(0);
  advance();
  stage(1);

  for (int t = 0; t < nt; ++t) {
    if (t + 2 < nt) {
      advance();
      stage((t + 2) & 3);
      // steady state: 2 stages (t+1, t+2) in flight -> wait step t complete
      if constexpr (LPS == 4) asm volatile("s_waitcnt vmcnt(8)" ::: "memory");
      else if constexpr (LPS == 3) asm volatile("s_waitcnt vmcnt(6)" ::: "memory");
      else asm volatile("s_waitcnt vmcnt(4)" ::: "memory");
    } else if (t + 2 == nt) {
      if constexpr (LPS == 4) asm volatile("s_waitcnt vmcnt(4)" ::: "memory");
      else if constexpr (LPS == 3) asm volatile("s_waitcnt vmcnt(3)" ::: "memory");
      else asm volatile("s_waitcnt vmcnt(2)" ::: "memory");
    } else {
      asm volatile("s_waitcnt vmcnt(0)" ::: "memory");
    }
    __builtin_amdgcn_s_barrier();

    const _Float16* pA = sA[t & 3];
    const _Float16* pB = sB[t & 3];
    f16x8 af[MF], bf[NF];
#pragma unroll
    for (int i = 0; i < MF; ++i)
      af[i] = *(const f16x8*)(pA + ((wm * (MF * 16) + (i << 4) + lc) << 5) + swz);
#pragma unroll
    for (int i = 0; i < NF; ++i)
      bf[i] = *(const f16x8*)(pB + ((wn * (NF * 16) + (i << 4) + lc) << 5) + swz);
#pragma unroll
    for (int mi = 0; mi < MF; ++mi)
#pragma unroll
      for (int ni = 0; ni < NF; ++ni)
        acc[mi][ni] =
            __builtin_amdgcn_mfma_f32_16x16x32_f16(af[mi], bf[ni], acc[mi][ni], 0, 0, 0);
    __builtin_amdgcn_s_barrier();
  }

  // Epilogue: D col = lane&15 -> pixel, row = lr*4+j -> cout
#pragma unroll
  for (int mi = 0; mi < MF; ++mi) {
    const int ob = m0 + wm * (MF * 16) + (mi << 4) + (lr << 2);
    const f32x4 gv = *(const f32x4*)(gg + ob);
    const f32x4 bv = *(const f32x4*)(bbv + ob);
    const f32x4 evv = *(const f32x4*)(ev + ob);
#pragma unroll
    for (int ni = 0; ni < NF; ++ni) {
      const int n = n0 + wn * (NF * 16) + (ni << 4) + lc;
      const int y = (n >> lw) & (H - 1);
      const int x = n & (W - 1);
      const int bb_ = n >> (lw + lh);
      const size_t op = (size_t)(bb_ * bso + y * Wpo + x + obase) * outS + outOff + ob;
      f16x4 h;
#pragma unroll
      for (int j = 0; j < 4; ++j) {
        const float s = gv[j] * BN_S;
        float v = acc[mi][ni][j] + (bv[j] * s + evv[j]);
        v = v > 0.f ? v : 0.f;
        h[j] = (_Float16)v;
      }
      *(f16x4*)(out + op) = h;
    }
  }
}

// ---------------------------------------------------------------------------
// conv1: Cin=3, Cout=64, 512x512, fp32 NCHW data + raw fp32 weights.
// ---------------------------------------------------------------------------
__global__ __launch_bounds__(256) void conv1_k(
    const float* __restrict__ data, const float* __restrict__ w1,
    const float* __restrict__ g1, const float* __restrict__ b1,
    const float* __restrict__ e1, _Float16* __restrict__ out) {
  __shared__ float patch[3][20][20];
  const int tid = threadIdx.x;
  const int bid = blockIdx.x;
  const int tx = bid & 31, ty = (bid >> 5) & 31, b = bid >> 10;

  for (int i = tid; i < 1200; i += 256) {
    const int c = i / 400;
    const int r = i - c * 400;
    const int pyy = r / 20;
    const int pxx = r - pyy * 20;
    const int gy = (ty << 4) + pyy - 2, gx = (tx << 4) + pxx - 2;
    float v = 0.f;
    if ((unsigned)gy < 512u && (unsigned)gx < 512u)
      v = data[((size_t)(b * 3 + c) << 18) + (gy << 9) + gx];
    patch[c][pyy][pxx] = v;
  }
  __syncthreads();

  const int py = tid >> 4, px = tid & 15;
  float acc[64];
#pragma unroll
  for (int o = 0; o < 64; ++o) acc[o] = 0.f;

  for (int c = 0; c < 3; ++c)
    for (int dy = 0; dy < 5; ++dy) {
#pragma unroll
      for (int dx = 0; dx < 5; ++dx) {
        const float v = patch[c][py + dy][px + dx];
        const float* wb = w1 + c * 25 + dy * 5 + dx;
#pragma unroll
        for (int o = 0; o < 64; ++o) acc[o] = fmaf(v, wb[o * 75], acc[o]);
      }
    }

  const int y = (ty << 4) + py, x = (tx << 4) + px;
  _Float16* op = out + ((size_t)(((b << 9) + y) << 9) + x) * 64;
#pragma unroll
  for (int oc = 0; oc < 8; ++oc) {
    f16x8 h;
#pragma unroll
    for (int j = 0; j < 8; ++j) {
      const int o = (oc << 3) + j;
      const float s = g1[o] * BN_S;
      const float t = b1[o] * s + e1[o];
      float v = fmaf(acc[o], s, t);
      v = v > 0.f ? v : 0.f;
      h[j] = (_Float16)v;
    }
    *(f16x8*)(op + (oc << 3)) = h;
  }
}

// ---------------------------------------------------------------------------
// avg-pool 2x2 stride 2, NHWC fp16, generic padded/unpadded addressing
// ---------------------------------------------------------------------------
__global__ void pool_k(const _Float16* __restrict__ in, _Float16* __restrict__ out,
                       int inS, int outS, int Wpi, int bsi, int ibase,
                       int Wpo, int bso, int obase,
                       int lwo, int lho, int lcc, int total) {
  const int idx = blockIdx.x * 256 + threadIdx.x;
  if (idx >= total) return;
  const int cc = idx & ((1 << lcc) - 1);
  const int pix = idx >> lcc;
  const int x = pix & ((1 << lwo) - 1);
  const int y = (pix >> lwo) & ((1 << lho) - 1);
  const int b = pix >> (lwo + lho);
  const int ip = b * bsi + (y << 1) * Wpi + (x << 1) + ibase;
  const _Float16* p = in + (size_t)ip * inS + (cc << 3);
  const f16x8 v00 = *(const f16x8*)p;
  const f16x8 v01 = *(const f16x8*)(p + inS);
  const f16x8 v10 = *(const f16x8*)(p + (size_t)Wpi * inS);
  const f16x8 v11 = *(const f16x8*)(p + (size_t)(Wpi + 1) * inS);
  f16x8 r;
#pragma unroll
  for (int j = 0; j < 8; ++j)
    r[j] = (_Float16)(((float)v00[j] + (float)v01[j] + (float)v10[j] + (float)v11[j]) * 0.25f);
  const int op = b * bso + y * Wpo + x + obase;
  *(f16x8*)(out + (size_t)op * outS + (cc << 3)) = r;
}

// ---------------------------------------------------------------------------
// bilinear 2x upsample (align_corners=True), NHWC fp16
// ---------------------------------------------------------------------------
__global__ void up_k(const _Float16* __restrict__ in, _Float16* __restrict__ out,
                     int inS, int outS, int outOff,
                     int Wpi, int bsi, int ibase,
                     int Wpo, int bso, int obase,
                     int lwi, int lhi, int lcc, float scale, int total) {
  const int idx = blockIdx.x * 256 + threadIdx.x;
  if (idx >= total) return;
  const int cc = idx & ((1 << lcc) - 1);
  const int pix = idx >> lcc;
  const int lwo = lwi + 1, lho = lhi + 1;
  const int ox = pix & ((1 << lwo) - 1);
  const int oy = (pix >> lwo) & ((1 << lho) - 1);
  const int b = pix >> (lwo + lho);
  const int Hi = 1 << lhi, Wi = 1 << lwi;
  const float fy = oy * scale;
  const int y0 = (int)fy;
  const float wy = fy - y0;
  const int y1 = min(y0 + 1, Hi - 1);
  const float fx = ox * scale;
  const int x0 = (int)fx;
  const float wx = fx - x0;
  const int x1 = min(x0 + 1, Wi - 1);
  const int rbase = b * bsi + ibase;
  const _Float16* basep = in + (cc << 3);
  const f16x8 v00 = *(const f16x8*)(basep + (size_t)(rbase + y0 * Wpi + x0) * inS);
  const f16x8 v01 = *(const f16x8*)(basep + (size_t)(rbase + y0 * Wpi + x1) * inS);
  const f16x8 v10 = *(const f16x8*)(basep + (size_t)(rbase + y1 * Wpi + x0) * inS);
  const f16x8 v11 = *(const f16x8*)(basep + (size_t)(rbase + y1 * Wpi + x1) * inS);
  f16x8 r;
#pragma unroll
  for (int j = 0; j < 8; ++j) {
    const float top = (float)v00[j] * (1.f - wx) + (float)v01[j] * wx;
    const float bot = (float)v10[j] * (1.f - wx) + (float)v11[j] * wx;
    r[j] = (_Float16)(top * (1.f - wy) + bot * wy);
  }
  const int op = b * bso + oy * Wpo + ox + obase;
  *(f16x8*)(out + (size_t)op * outS + outOff + (cc << 3)) = r;
}

// ---------------------------------------------------------------------------
// conv8 (LDS-tiled): Cin=384 (= c2[128ch] ++ up7[256ch]), Cout=3, 256x256.
// ---------------------------------------------------------------------------
__global__ __launch_bounds__(256) void conv8_lds(
    const _Float16* __restrict__ inA, const _Float16* __restrict__ inB,
    const _Float16* __restrict__ wt, const float* __restrict__ b8,
    const float* __restrict__ g8, const float* __restrict__ e8,
    _Float16* __restrict__ out) {
  __shared__ f16x8 patch[2][20][20];
  const int tid = threadIdx.x;
  const int bid = blockIdx.x;  // 512
  const int tx = bid & 15, ty = (bid >> 4) & 15, b = bid >> 8;
  const int px = tid & 15, py = tid >> 4;
  const int x0 = tx << 4, y0 = ty << 4;

  float a0 = 0.f, a1 = 0.f, a2 = 0.f;
  for (int c = 0; c < 48; ++c) {
    const _Float16* sbase;
    int str;
    if (c < 16) { sbase = inA + ((size_t)b << 23) + (c << 3); str = 128; }
    else        { sbase = inB + ((size_t)b << 24) + ((c - 16) << 3); str = 256; }
    for (int i = tid; i < 400; i += 256) {
      const int pyy = i / 20, pxx = i - pyy * 20;
      const int gy = y0 + pyy - 2, gx = x0 + pxx - 2;
      f16x8 v = f16x8_zero();
      if ((unsigned)gy < 256u && (unsigned)gx < 256u)
        v = *(const f16x8*)(sbase + (size_t)((gy << 8) + gx) * str);
      patch[c & 1][pyy][pxx] = v;
    }
    __syncthreads();
    const _Float16* wb_c = wt + c * 600;
#pragma unroll
    for (int dy = 0; dy < 5; ++dy) {
#pragma unroll
      for (int dxx = 0; dxx < 5; ++dxx) {
        const f16x8 v = patch[c & 1][py + dy][px + dxx];
        const _Float16* wb = wb_c + (dy * 5 + dxx) * 24;
#pragma unroll
        for (int j = 0; j < 8; ++j) {
          const float f = (float)v[j];
          a0 = fmaf(f, (float)wb[j], a0);
          a1 = fmaf(f, (float)wb[8 + j], a1);
          a2 = fmaf(f, (float)wb[16 + j], a2);
        }
      }
    }
  }

  const float s0 = g8[0] * BN_S, t0 = b8[0] * s0 + e8[0];
  const float s1 = g8[1] * BN_S, t1 = b8[1] * s1 + e8[1];
  const float s2 = g8[2] * BN_S, t2 = b8[2] * s2 + e8[2];
  float r0 = a0 + t0, r1 = a1 + t1, r2 = a2 + t2;
  r0 = r0 > 0.f ? r0 : 0.f;
  r1 = r1 > 0.f ? r1 : 0.f;
  r2 = r2 > 0.f ? r2 : 0.f;
  f16x4 h;
  h[0] = (_Float16)r0; h[1] = (_Float16)r1; h[2] = (_Float16)r2; h[3] = (_Float16)0.f;
  const int opix = (b << 16) + ((y0 + py) << 8) + (x0 + px);
  *(f16x4*)(out + (size_t)opix * 4) = h;
}

// ---------------------------------------------------------------------------
// final: bilinear up(c8, 256->512) + 1x1 conv (wo,bo) + out = data*core (fp32)
// ---------------------------------------------------------------------------
__global__ void final_k(const float* __restrict__ data, const _Float16* __restrict__ c8,
                        const float* __restrict__ wo, const float* __restrict__ bo,
                        float* __restrict__ out) {
  const int idx = blockIdx.x * 256 + threadIdx.x;  // < 524288
  const int x = idx & 511, y = (idx >> 9) & 511, b = idx >> 18;
  const float sc = 255.f / 511.f;
  const float fy = y * sc;
  const int y0 = (int)fy;
  const float wy = fy - y0;
  const int y1 = min(y0 + 1, 255);
  const float fx = x * sc;
  const int x0 = (int)fx;
  const float wx = fx - x0;
  const int x1 = min(x0 + 1, 255);
  const f16x4 v00 = *(const f16x4*)(c8 + (size_t)((((b << 8) + y0) << 8) + x0) * 4);
  const f16x4 v01 = *(const f16x4*)(c8 + (size_t)((((b << 8) + y0) << 8) + x1) * 4);
  const f16x4 v10 = *(const f16x4*)(c8 + (size_t)((((b << 8) + y1) << 8) + x0) * 4);
  const f16x4 v11 = *(const f16x4*)(c8 + (size_t)((((b << 8) + y1) << 8) + x1) * 4);
  float u[3];
#pragma unroll
  for (int j = 0; j < 3; ++j) {
    const float top = (float)v00[j] * (1.f - wx) + (float)v01[j] * wx;
    const float bot = (float)v10[j] * (1.f - wx) + (float)v11[j] * wx;
    u[j] = top * (1.f - wy) + bot * wy;
  }
#pragma unroll
  for (int c = 0; c < 3; ++c) {
    const float core = bo[c] + wo[c * 3 + 0] * u[0] + wo[c * 3 + 1] * u[1] + wo[c * 3 + 2] * u[2];
    const size_t oi = ((size_t)(b * 3 + c) << 18) + (y << 9) + x;
    out[oi] = data[oi] * core;
  }
}

// ---------------------------------------------------------------------------
extern "C" void kernel_launch(void* const* d_in, const int* in_sizes, int n_in,
                              void* d_out, int out_size, void* d_ws, size_t ws_size,
                              hipStream_t stream) {
  const float* data = (const float*)d_in[0];
  const float *w[9], *bb[9], *gg[9], *ee[9];
  for (int n = 1; n <= 8; ++n) {
    w[n] = (const float*)d_in[1 + (n - 1) * 4];
    bb[n] = (const float*)d_in[2 + (n - 1) * 4];
    gg[n] = (const float*)d_in[3 + (n - 1) * 4];
    ee[n] = (const float*)d_in[4 + (n - 1) * 4];
  }
  const float* wo = (const float*)d_in[33];
  const float* bo = (const float*)d_in[34];
  float* out = (float*)d_out;
  (void)in_sizes; (void)n_in;

  // ---- workspace layout (aliased; padded activations; 194,810,112 B) ----
  const size_t NEEDED = 194810112ull;
  if (ws_size < NEEDED) {
    zero_out_k<<<(out_size + 255) / 256, 256, 0, stream>>>(out, out_size);
    return;
  }
  char* base = (char*)d_ws;
  size_t off = 0;
  auto alloc = [&](size_t bytes) -> char* {
    char* p = base + off;
    off += (bytes + 255) & ~(size_t)255;
    return p;
  };
  _Float16* W2t = (_Float16*)alloc(409600);     // 25*128*64*2
  _Float16* W3t = (_Float16*)alloc(1638400);    // 25*256*128*2
  _Float16* W4t = (_Float16*)alloc(6553600);    // 25*512*256*2
  _Float16* W5t = (_Float16*)alloc(13107200);   // 25*512*512*2
  _Float16* W6t = (_Float16*)alloc(26214400);   // 25*512*1024*2
  _Float16* W7t = (_Float16*)alloc(9830400);    // 25*256*768*2
  _Float16* W8t = (_Float16*)alloc(57600);      // 48*25*24 fp16
  char* Rbig = alloc(72466432);   // c1(67.1M) | cat7(53.5M)+cat6(18.9M) | up7(67.1M)
  char* c2b_ = alloc(33554432);   // c2 (2,256,256,128) unpadded
  char* R1 = alloc(17305600);     // p1(17.3M) | c6(8.4M) | c7(16.8M) | c8(1M)
  char* R2 = alloc(13672448);     // p2(8.9M) ; [p3(4.7M) | p4(2.65M)+c5(2.1M)]

  _Float16* c1 = (_Float16*)Rbig;                    // (2,512,512,64) unpadded
  _Float16* cat7 = (_Float16*)Rbig;                  // (2,132,132,768) padded
  _Float16* cat6 = (_Float16*)(Rbig + 53526528);     // (2,68,68,1024) padded
  _Float16* up7b = (_Float16*)Rbig;                  // (2,256,256,256) unpadded
  _Float16* c2buf = (_Float16*)c2b_;                 // (2,256,256,128) unpadded
  _Float16* p1 = (_Float16*)R1;                      // (2,260,260,64) padded
  _Float16* c6 = (_Float16*)R1;                      // (2,64,64,512) unpadded
  _Float16* c7 = (_Float16*)R1;                      // (2,128,128,256) unpadded
  _Float16* c8 = (_Float16*)R1;                      // (2,256,256,4) unpadded
  _Float16* p2 = (_Float16*)R2;                      // (2,132,132,128) padded
  _Float16* p3 = (_Float16*)(R2 + 8921088);          // (2,68,68,256) padded
  _Float16* p4 = (_Float16*)(R2 + 8921088);          // (2,36,36,512) padded (aliases p3!)
  _Float16* c5 = (_Float16*)(R2 + 8921088 + 2654208);// (2,32,32,512) unpadded

  // zero halo buffers not aliased with earlier-live data.
  // NOTE: p4 aliases p3, so p4's halo must be zeroed AFTER conv4 (p3 dead).
  zero16_k<<<(1081600 + 255) / 256, 256, 0, stream>>>(p1, 1081600);   // 17.3MB
  zero16_k<<<(557568 + 255) / 256, 256, 0, stream>>>(p2, 557568);     // 8.9MB
  zero16_k<<<(295936 + 255) / 256, 256, 0, stream>>>(p3, 295936);     // 4.7MB

  // weight transforms (fold BN scale into weights)
  wtrans16<<<(25 * 128 * 64 + 255) / 256, 256, 0, stream>>>(w[2], W2t, gg[2], 128, 64, 25 * 128 * 64);
  wtrans16<<<(25 * 256 * 128 + 255) / 256, 256, 0, stream>>>(w[3], W3t, gg[3], 256, 128, 25 * 256 * 128);
  wtrans16<<<(25 * 512 * 256 + 255) / 256, 256, 0, stream>>>(w[4], W4t, gg[4], 512, 256, 25 * 512 * 256);
  wtrans16<<<(25 * 512 * 512 + 255) / 256, 256, 0, stream>>>(w[5], W5t, gg[5], 512, 512, 25 * 512 * 512);
  wtrans16<<<(25 * 512 * 1024 + 255) / 256, 256, 0, stream>>>(w[6], W6t, gg[6], 512, 1024, 25 * 512 * 1024);
  wtrans16<<<(25 * 256 * 768 + 255) / 256, 256, 0, stream>>>(w[7], W7t, gg[7], 256, 768, 25 * 256 * 768);
  wtrans8<<<(28800 + 255) / 256, 256, 0, stream>>>(w[8], W8t, gg[8]);

  conv1_k<<<2048, 256, 0, stream>>>(data, w[1], gg[1], bb[1], ee[1], c1);
  pool_k<<<1048576 / 256, 256, 0, stream>>>(c1, p1, 64, 64, 512, 262144, 0,
                                            260, 67600, 522, 8, 8, 3, 1048576);
  // c1 dead -> zero cat7/cat6 (they alias c1's region)
  zero16_k<<<(3345408 + 255) / 256, 256, 0, stream>>>(cat7, 3345408);  // 53.5MB
  zero16_k<<<(1183744 + 255) / 256, 256, 0, stream>>>(cat6, 1183744);  // 18.9MB

  conv_gemm<4, 4><<<dim3(1024, 1), 256, 0, stream>>>(p1, W2t, gg[2], bb[2], ee[2], c2buf,
      64, 128, 8, 8, 64, 260, 67600, 522, 128, 0, 256, 65536, 0);
  pool_k<<<524288 / 256, 256, 0, stream>>>(c2buf, p2, 128, 128, 256, 65536, 0,
                                           132, 17424, 266, 7, 7, 4, 524288);
  conv_gemm<4, 4><<<dim3(256, 2), 256, 0, stream>>>(p2, W3t, gg[3], bb[3], ee[3], cat7,
      128, 256, 7, 7, 128, 132, 17424, 266, 768, 0, 132, 17424, 266);
  pool_k<<<262144 / 256, 256, 0, stream>>>(cat7, p3, 768, 256, 132, 17424, 266,
                                           68, 4624, 138, 6, 6, 5, 262144);
  conv_gemm<4, 4><<<dim3(64, 4), 256, 0, stream>>>(p3, W4t, gg[4], bb[4], ee[4], cat6,
      256, 512, 6, 6, 256, 68, 4624, 138, 1024, 0, 68, 4624, 138);
  // p3 dead -> now safe to zero p4's halo (p4 aliases p3's bytes)
  zero16_k<<<(165888 + 255) / 256, 256, 0, stream>>>(p4, 165888);      // 2.65MB
  pool_k<<<131072 / 256, 256, 0, stream>>>(cat6, p4, 1024, 512, 68, 4624, 138,
                                           36, 1296, 74, 5, 5, 6, 131072);
  conv_gemm<2, 2><<<dim3(32, 8), 256, 0, stream>>>(p4, W5t, gg[5], bb[5], ee[5], c5,
      512, 512, 5, 5, 512, 36, 1296, 74, 512, 0, 32, 1024, 0);
  up_k<<<524288 / 256, 256, 0, stream>>>(c5, cat6, 512, 1024, 512,
                                         32, 1024, 0, 68, 4624, 138,
                                         5, 5, 6, 31.f / 63.f, 524288);
  conv_gemm<4, 4><<<dim3(64, 4), 256, 0, stream>>>(cat6, W6t, gg[6], bb[6], ee[6], c6,
      1024, 512, 6, 6, 1024, 68, 4624, 138, 512, 0, 64, 4096, 0);
  up_k<<<2097152 / 256, 256, 0, stream>>>(c6, cat7, 512, 768, 256,
                                          64, 4096, 0, 132, 17424, 266,
                                          6, 6, 6, 63.f / 127.f, 2097152);
  conv_gemm<4, 4><<<dim3(256, 2), 256, 0, stream>>>(cat7, W7t, gg[7], bb[7], ee[7], c7,
      768, 256, 7, 7, 768, 132, 17424, 266, 256, 0, 128, 16384, 0);
  up_k<<<4194304 / 256, 256, 0, stream>>>(c7, up7b, 256, 256, 0,
                                          128, 16384, 0, 256, 65536, 0,
                                          7, 7, 5, 127.f / 255.f, 4194304);
  conv8_lds<<<512, 256, 0, stream>>>(c2buf, up7b, W8t, bb[8], gg[8], ee[8], c8);
  final_k<<<524288 / 256, 256, 0, stream>>>(data, c8, wo, bo, out);
}

// Round 8
// 1939.242 us; speedup vs baseline: 1.0633x; 1.0633x over previous
//
#include <hip/hip_runtime.h>
#include <hip/hip_bf16.h>

typedef _Float16 f16x8 __attribute__((ext_vector_type(8)));
typedef _Float16 f16x4 __attribute__((ext_vector_type(4)));
typedef float f32x4 __attribute__((ext_vector_type(4)));

#define BN_S 0.99999500003749975f  // 1/sqrt(1+1e-5)

__device__ inline f16x8 f16x8_zero() {
  f16x8 v = {(_Float16)0.f, (_Float16)0.f, (_Float16)0.f, (_Float16)0.f,
             (_Float16)0.f, (_Float16)0.f, (_Float16)0.f, (_Float16)0.f};
  return v;
}

__device__ __forceinline__ void load_lds16(const _Float16* g, _Float16* l) {
  __builtin_amdgcn_global_load_lds(
      (const __attribute__((address_space(1))) void*)g,
      (__attribute__((address_space(3))) void*)l, 16, 0, 0);
}

__global__ void zero_out_k(float* __restrict__ out, int n) {
  const int idx = blockIdx.x * 256 + threadIdx.x;
  if (idx < n) out[idx] = 0.f;
}

// zero n16 16-byte blocks
__global__ void zero16_k(_Float16* __restrict__ p, int n16) {
  const int idx = blockIdx.x * 256 + threadIdx.x;
  if (idx < n16) ((f16x8*)p)[idx] = f16x8_zero();
}

// ---------------------------------------------------------------------------
// Weight transform: OIHW fp32 -> [25][O][C] fp16, pre-scaled by g*BN_S.
// ---------------------------------------------------------------------------
__global__ void wtrans16(const float* __restrict__ src, _Float16* __restrict__ dst,
                         const float* __restrict__ g, int O, int C, int total) {
  const int idx = blockIdx.x * 256 + threadIdx.x;  // (t, o, c)
  if (idx >= total) return;
  const int OC = O * C;
  const int t = idx / OC;
  const int rem = idx - t * OC;
  const int o = rem / C;
  const int c = rem - o * C;
  dst[idx] = (_Float16)(src[(size_t)(o * C + c) * 25 + t] * g[o] * BN_S);
}

// conv8 weights: OIHW fp32 (O=3,C=384) -> [48 chunks][25 taps][3][8] fp16.
__global__ void wtrans8(const float* __restrict__ src, _Float16* __restrict__ dst,
                        const float* __restrict__ g) {
  const int idx = blockIdx.x * 256 + threadIdx.x;
  if (idx >= 28800) return;
  const int c = idx / 600;
  const int r = idx - c * 600;
  const int tap = r / 24;
  const int q = r - tap * 24;
  const int o = q >> 3, j = q & 7;
  const int cin = (c < 16) ? (c * 8 + j) : (128 + (c - 16) * 8 + j);
  dst[idx] = (_Float16)(src[((size_t)o * 384 + cin) * 25 + tap] * g[o] * BN_S);
}

// ---------------------------------------------------------------------------
// Implicit-GEMM 5x5 conv + BN + ReLU.  Cin%(32*KS)==0, Cout%BM==0, px%BN==0.
// in: padded NHWC fp16 (2-px zero halo), wt: [25][Cout][Cin] fp16 prescaled.
// Block tile BM(cout) x BN(px); 4 waves 2x2; KS k-steps (32 ch each) staged
// per barrier into double-buffered LDS via global_load_lds(16B).
// XOR-swizzled LDS: halfword(row,chunk) = row*32 + (chunk^((row>>1)&3))*8
// Proven round-4 __syncthreads structure (1 barrier per staged group).
// ---------------------------------------------------------------------------
template <int MF, int NF, int KS>
__global__ __launch_bounds__(256) void conv_gemm(
    const _Float16* __restrict__ in, const _Float16* __restrict__ wt,
    const float* __restrict__ gg, const float* __restrict__ bbv,
    const float* __restrict__ ev, _Float16* __restrict__ out,
    int Cin, int Cout, int lw, int lh,
    int inS, int Wpi, int bsi, int ibase,
    int outS, int outOff, int Wpo, int bso, int obase) {
  constexpr int BM = MF * 32;
  constexpr int BN = NF * 32;
  constexpr int SUB_A = BM * 32;  // halfwords per k-substep
  constexpr int SUB_B = BN * 32;
  __shared__ _Float16 sA[2][SUB_A * KS];
  __shared__ _Float16 sB[2][SUB_B * KS];

  const int tid = threadIdx.x;
  const int lane = tid & 63;
  const int wid = tid >> 6;
  const int wm = wid >> 1, wn = wid & 1;
  const int lr = lane >> 4, lc = lane & 15;
  const int n0 = blockIdx.x * BN;
  const int m0 = blockIdx.y * BM;
  const int H = 1 << lh, W = 1 << lw;
  const int nkb = Cin >> 5;

  // staging identity: linear g = issue*256 + tid; row=g>>2, slot=g&3
  const int r0 = tid >> 2;
  const int chunk = (tid & 3) ^ ((r0 >> 1) & 3);  // same for row r0+64

  const _Float16* a0 = wt + (size_t)(m0 + r0) * Cin + (chunk << 3);
  const _Float16* a1 = a0 + ((size_t)Cin << 6);  // used only if BM==128
  const int t0off = -2 * Wpi - 2;  // tap (dy=0,dx=0)
  const _Float16 *b0, *b1 = nullptr;
  {
    int n = n0 + r0;
    int pix0 = (n >> (lw + lh)) * bsi + ((n >> lw) & (H - 1)) * Wpi + (n & (W - 1)) + ibase;
    b0 = in + (size_t)(pix0 + t0off) * inS + (chunk << 3);
    if constexpr (BN == 128) {
      n = n0 + r0 + 64;
      int pix1 = (n >> (lw + lh)) * bsi + ((n >> lw) & (H - 1)) * Wpi + (n & (W - 1)) + ibase;
      b1 = in + (size_t)(pix1 + t0off) * inS + (chunk << 3);
    }
  }

  // ds_read fragment swizzle (halfwords)
  const int swz = (lr ^ ((lc >> 1) & 3)) << 3;

  f32x4 acc[MF][NF];
  const f32x4 vz = {0.f, 0.f, 0.f, 0.f};
#pragma unroll
  for (int i = 0; i < MF; ++i)
#pragma unroll
    for (int j = 0; j < NF; ++j) acc[i][j] = vz;

  const int np = 25 * nkb / KS;  // staged groups
  int kb = 0, dx = 0;
  const size_t a_tap = (size_t)Cout * Cin - ((size_t)nkb << 5);
  const int woff = wid << 9;  // wave LDS base within a 4KB issue (halfwords)

  // advance staging pointers by one group (KS k-steps)
  auto advance = [&]() {
    a0 += 32 * KS; b0 += 32 * KS;
    if constexpr (BM == 128) a1 += 32 * KS;
    if constexpr (BN == 128) b1 += 32 * KS;
    kb += KS;
    if (kb == nkb) {
      kb = 0;
      a0 += a_tap;
      if constexpr (BM == 128) a1 += a_tap;
      int pd;
      if (++dx == 5) { dx = 0; pd = Wpi - 4; } else pd = 1;
      const ptrdiff_t bd = (ptrdiff_t)pd * inS - ((ptrdiff_t)nkb << 5);
      b0 += bd;
      if constexpr (BN == 128) b1 += bd;
    }
  };
  auto stage = [&](int buf) {
#pragma unroll
    for (int s = 0; s < KS; ++s) {
      _Float16* sa = sA[buf] + s * SUB_A + woff;
      _Float16* sb = sB[buf] + s * SUB_B + woff;
      load_lds16(a0 + 32 * s, sa);
      if constexpr (BM == 128) load_lds16(a1 + 32 * s, sa + 2048);
      load_lds16(b0 + 32 * s, sb);
      if constexpr (BN == 128) load_lds16(b1 + 32 * s, sb + 2048);
    }
  };

  // prologue: stage group 0 into buf 0
  stage(0);
  __syncthreads();

  int cur = 0;
  for (int t = 0; t < np; ++t) {
    if (t + 1 < np) {
      advance();
      stage(cur ^ 1);
    }
    const _Float16* pA = sA[cur];
    const _Float16* pB = sB[cur];
#pragma unroll
    for (int s = 0; s < KS; ++s) {
      f16x8 af[MF], bf[NF];
#pragma unroll
      for (int i = 0; i < MF; ++i)
        af[i] = *(const f16x8*)(pA + s * SUB_A + ((wm * (MF * 16) + (i << 4) + lc) << 5) + swz);
#pragma unroll
      for (int i = 0; i < NF; ++i)
        bf[i] = *(const f16x8*)(pB + s * SUB_B + ((wn * (NF * 16) + (i << 4) + lc) << 5) + swz);
#pragma unroll
      for (int mi = 0; mi < MF; ++mi)
#pragma unroll
        for (int ni = 0; ni < NF; ++ni)
          acc[mi][ni] =
              __builtin_amdgcn_mfma_f32_16x16x32_f16(af[mi], bf[ni], acc[mi][ni], 0, 0, 0);
    }
    __syncthreads();  // drains stage(cur^1) loads + fences buf reuse
    cur ^= 1;
  }

  // Epilogue: D col = lane&15 -> pixel, row = lr*4+j -> cout
#pragma unroll
  for (int mi = 0; mi < MF; ++mi) {
    const int ob = m0 + wm * (MF * 16) + (mi << 4) + (lr << 2);
    const f32x4 gv = *(const f32x4*)(gg + ob);
    const f32x4 bv = *(const f32x4*)(bbv + ob);
    const f32x4 evv = *(const f32x4*)(ev + ob);
#pragma unroll
    for (int ni = 0; ni < NF; ++ni) {
      const int n = n0 + wn * (NF * 16) + (ni << 4) + lc;
      const int y = (n >> lw) & (H - 1);
      const int x = n & (W - 1);
      const int bb_ = n >> (lw + lh);
      const size_t op = (size_t)(bb_ * bso + y * Wpo + x + obase) * outS + outOff + ob;
      f16x4 h;
#pragma unroll
      for (int j = 0; j < 4; ++j) {
        const float s = gv[j] * BN_S;
        float v = acc[mi][ni][j] + (bv[j] * s + evv[j]);
        v = v > 0.f ? v : 0.f;
        h[j] = (_Float16)v;
      }
      *(f16x4*)(out + op) = h;
    }
  }
}

// ---------------------------------------------------------------------------
// conv1: Cin=3, Cout=64, 512x512, fp32 NCHW data + raw fp32 weights.
// ---------------------------------------------------------------------------
__global__ __launch_bounds__(256) void conv1_k(
    const float* __restrict__ data, const float* __restrict__ w1,
    const float* __restrict__ g1, const float* __restrict__ b1,
    const float* __restrict__ e1, _Float16* __restrict__ out) {
  __shared__ float patch[3][20][20];
  const int tid = threadIdx.x;
  const int bid = blockIdx.x;
  const int tx = bid & 31, ty = (bid >> 5) & 31, b = bid >> 10;

  for (int i = tid; i < 1200; i += 256) {
    const int c = i / 400;
    const int r = i - c * 400;
    const int pyy = r / 20;
    const int pxx = r - pyy * 20;
    const int gy = (ty << 4) + pyy - 2, gx = (tx << 4) + pxx - 2;
    float v = 0.f;
    if ((unsigned)gy < 512u && (unsigned)gx < 512u)
      v = data[((size_t)(b * 3 + c) << 18) + (gy << 9) + gx];
    patch[c][pyy][pxx] = v;
  }
  __syncthreads();

  const int py = tid >> 4, px = tid & 15;
  float acc[64];
#pragma unroll
  for (int o = 0; o < 64; ++o) acc[o] = 0.f;

  for (int c = 0; c < 3; ++c)
    for (int dy = 0; dy < 5; ++dy) {
#pragma unroll
      for (int dx = 0; dx < 5; ++dx) {
        const float v = patch[c][py + dy][px + dx];
        const float* wb = w1 + c * 25 + dy * 5 + dx;
#pragma unroll
        for (int o = 0; o < 64; ++o) acc[o] = fmaf(v, wb[o * 75], acc[o]);
      }
    }

  const int y = (ty << 4) + py, x = (tx << 4) + px;
  _Float16* op = out + ((size_t)(((b << 9) + y) << 9) + x) * 64;
#pragma unroll
  for (int oc = 0; oc < 8; ++oc) {
    f16x8 h;
#pragma unroll
    for (int j = 0; j < 8; ++j) {
      const int o = (oc << 3) + j;
      const float s = g1[o] * BN_S;
      const float t = b1[o] * s + e1[o];
      float v = fmaf(acc[o], s, t);
      v = v > 0.f ? v : 0.f;
      h[j] = (_Float16)v;
    }
    *(f16x8*)(op + (oc << 3)) = h;
  }
}

// ---------------------------------------------------------------------------
// avg-pool 2x2 stride 2, NHWC fp16, generic padded/unpadded addressing
// ---------------------------------------------------------------------------
__global__ void pool_k(const _Float16* __restrict__ in, _Float16* __restrict__ out,
                       int inS, int outS, int Wpi, int bsi, int ibase,
                       int Wpo, int bso, int obase,
                       int lwo, int lho, int lcc, int total) {
  const int idx = blockIdx.x * 256 + threadIdx.x;
  if (idx >= total) return;
  const int cc = idx & ((1 << lcc) - 1);
  const int pix = idx >> lcc;
  const int x = pix & ((1 << lwo) - 1);
  const int y = (pix >> lwo) & ((1 << lho) - 1);
  const int b = pix >> (lwo + lho);
  const int ip = b * bsi + (y << 1) * Wpi + (x << 1) + ibase;
  const _Float16* p = in + (size_t)ip * inS + (cc << 3);
  const f16x8 v00 = *(const f16x8*)p;
  const f16x8 v01 = *(const f16x8*)(p + inS);
  const f16x8 v10 = *(const f16x8*)(p + (size_t)Wpi * inS);
  const f16x8 v11 = *(const f16x8*)(p + (size_t)(Wpi + 1) * inS);
  f16x8 r;
#pragma unroll
  for (int j = 0; j < 8; ++j)
    r[j] = (_Float16)(((float)v00[j] + (float)v01[j] + (float)v10[j] + (float)v11[j]) * 0.25f);
  const int op = b * bso + y * Wpo + x + obase;
  *(f16x8*)(out + (size_t)op * outS + (cc << 3)) = r;
}

// ---------------------------------------------------------------------------
// bilinear 2x upsample (align_corners=True), NHWC fp16
// ---------------------------------------------------------------------------
__global__ void up_k(const _Float16* __restrict__ in, _Float16* __restrict__ out,
                     int inS, int outS, int outOff,
                     int Wpi, int bsi, int ibase,
                     int Wpo, int bso, int obase,
                     int lwi, int lhi, int lcc, float scale, int total) {
  const int idx = blockIdx.x * 256 + threadIdx.x;
  if (idx >= total) return;
  const int cc = idx & ((1 << lcc) - 1);
  const int pix = idx >> lcc;
  const int lwo = lwi + 1, lho = lhi + 1;
  const int ox = pix & ((1 << lwo) - 1);
  const int oy = (pix >> lwo) & ((1 << lho) - 1);
  const int b = pix >> (lwo + lho);
  const int Hi = 1 << lhi, Wi = 1 << lwi;
  const float fy = oy * scale;
  const int y0 = (int)fy;
  const float wy = fy - y0;
  const int y1 = min(y0 + 1, Hi - 1);
  const float fx = ox * scale;
  const int x0 = (int)fx;
  const float wx = fx - x0;
  const int x1 = min(x0 + 1, Wi - 1);
  const int rbase = b * bsi + ibase;
  const _Float16* basep = in + (cc << 3);
  const f16x8 v00 = *(const f16x8*)(basep + (size_t)(rbase + y0 * Wpi + x0) * inS);
  const f16x8 v01 = *(const f16x8*)(basep + (size_t)(rbase + y0 * Wpi + x1) * inS);
  const f16x8 v10 = *(const f16x8*)(basep + (size_t)(rbase + y1 * Wpi + x0) * inS);
  const f16x8 v11 = *(const f16x8*)(basep + (size_t)(rbase + y1 * Wpi + x1) * inS);
  f16x8 r;
#pragma unroll
  for (int j = 0; j < 8; ++j) {
    const float top = (float)v00[j] * (1.f - wx) + (float)v01[j] * wx;
    const float bot = (float)v10[j] * (1.f - wx) + (float)v11[j] * wx;
    r[j] = (_Float16)(top * (1.f - wy) + bot * wy);
  }
  const int op = b * bso + oy * Wpo + ox + obase;
  *(f16x8*)(out + (size_t)op * outS + outOff + (cc << 3)) = r;
}

// ---------------------------------------------------------------------------
// conv8 (LDS-tiled): Cin=384 (= c2[128ch] ++ up7[256ch]), Cout=3, 256x256.
// ---------------------------------------------------------------------------
__global__ __launch_bounds__(256) void conv8_lds(
    const _Float16* __restrict__ inA, const _Float16* __restrict__ inB,
    const _Float16* __restrict__ wt, const float* __restrict__ b8,
    const float* __restrict__ g8, const float* __restrict__ e8,
    _Float16* __restrict__ out) {
  __shared__ f16x8 patch[2][20][20];
  const int tid = threadIdx.x;
  const int bid = blockIdx.x;  // 512
  const int tx = bid & 15, ty = (bid >> 4) & 15, b = bid >> 8;
  const int px = tid & 15, py = tid >> 4;
  const int x0 = tx << 4, y0 = ty << 4;

  float a0 = 0.f, a1 = 0.f, a2 = 0.f;
  for (int c = 0; c < 48; ++c) {
    const _Float16* sbase;
    int str;
    if (c < 16) { sbase = inA + ((size_t)b << 23) + (c << 3); str = 128; }
    else        { sbase = inB + ((size_t)b << 24) + ((c - 16) << 3); str = 256; }
    for (int i = tid; i < 400; i += 256) {
      const int pyy = i / 20, pxx = i - pyy * 20;
      const int gy = y0 + pyy - 2, gx = x0 + pxx - 2;
      f16x8 v = f16x8_zero();
      if ((unsigned)gy < 256u && (unsigned)gx < 256u)
        v = *(const f16x8*)(sbase + (size_t)((gy << 8) + gx) * str);
      patch[c & 1][pyy][pxx] = v;
    }
    __syncthreads();
    const _Float16* wb_c = wt + c * 600;
#pragma unroll
    for (int dy = 0; dy < 5; ++dy) {
#pragma unroll
      for (int dxx = 0; dxx < 5; ++dxx) {
        const f16x8 v = patch[c & 1][py + dy][px + dxx];
        const _Float16* wb = wb_c + (dy * 5 + dxx) * 24;
#pragma unroll
        for (int j = 0; j < 8; ++j) {
          const float f = (float)v[j];
          a0 = fmaf(f, (float)wb[j], a0);
          a1 = fmaf(f, (float)wb[8 + j], a1);
          a2 = fmaf(f, (float)wb[16 + j], a2);
        }
      }
    }
  }

  const float s0 = g8[0] * BN_S, t0 = b8[0] * s0 + e8[0];
  const float s1 = g8[1] * BN_S, t1 = b8[1] * s1 + e8[1];
  const float s2 = g8[2] * BN_S, t2 = b8[2] * s2 + e8[2];
  float r0 = a0 + t0, r1 = a1 + t1, r2 = a2 + t2;
  r0 = r0 > 0.f ? r0 : 0.f;
  r1 = r1 > 0.f ? r1 : 0.f;
  r2 = r2 > 0.f ? r2 : 0.f;
  f16x4 h;
  h[0] = (_Float16)r0; h[1] = (_Float16)r1; h[2] = (_Float16)r2; h[3] = (_Float16)0.f;
  const int opix = (b << 16) + ((y0 + py) << 8) + (x0 + px);
  *(f16x4*)(out + (size_t)opix * 4) = h;
}

// ---------------------------------------------------------------------------
// final: bilinear up(c8, 256->512) + 1x1 conv (wo,bo) + out = data*core (fp32)
// ---------------------------------------------------------------------------
__global__ void final_k(const float* __restrict__ data, const _Float16* __restrict__ c8,
                        const float* __restrict__ wo, const float* __restrict__ bo,
                        float* __restrict__ out) {
  const int idx = blockIdx.x * 256 + threadIdx.x;  // < 524288
  const int x = idx & 511, y = (idx >> 9) & 511, b = idx >> 18;
  const float sc = 255.f / 511.f;
  const float fy = y * sc;
  const int y0 = (int)fy;
  const float wy = fy - y0;
  const int y1 = min(y0 + 1, 255);
  const float fx = x * sc;
  const int x0 = (int)fx;
  const float wx = fx - x0;
  const int x1 = min(x0 + 1, 255);
  const f16x4 v00 = *(const f16x4*)(c8 + (size_t)((((b << 8) + y0) << 8) + x0) * 4);
  const f16x4 v01 = *(const f16x4*)(c8 + (size_t)((((b << 8) + y0) << 8) + x1) * 4);
  const f16x4 v10 = *(const f16x4*)(c8 + (size_t)((((b << 8) + y1) << 8) + x0) * 4);
  const f16x4 v11 = *(const f16x4*)(c8 + (size_t)((((b << 8) + y1) << 8) + x1) * 4);
  float u[3];
#pragma unroll
  for (int j = 0; j < 3; ++j) {
    const float top = (float)v00[j] * (1.f - wx) + (float)v01[j] * wx;
    const float bot = (float)v10[j] * (1.f - wx) + (float)v11[j] * wx;
    u[j] = top * (1.f - wy) + bot * wy;
  }
#pragma unroll
  for (int c = 0; c < 3; ++c) {
    const float core = bo[c] + wo[c * 3 + 0] * u[0] + wo[c * 3 + 1] * u[1] + wo[c * 3 + 2] * u[2];
    const size_t oi = ((size_t)(b * 3 + c) << 18) + (y << 9) + x;
    out[oi] = data[oi] * core;
  }
}

// ---------------------------------------------------------------------------
extern "C" void kernel_launch(void* const* d_in, const int* in_sizes, int n_in,
                              void* d_out, int out_size, void* d_ws, size_t ws_size,
                              hipStream_t stream) {
  const float* data = (const float*)d_in[0];
  const float *w[9], *bb[9], *gg[9], *ee[9];
  for (int n = 1; n <= 8; ++n) {
    w[n] = (const float*)d_in[1 + (n - 1) * 4];
    bb[n] = (const float*)d_in[2 + (n - 1) * 4];
    gg[n] = (const float*)d_in[3 + (n - 1) * 4];
    ee[n] = (const float*)d_in[4 + (n - 1) * 4];
  }
  const float* wo = (const float*)d_in[33];
  const float* bo = (const float*)d_in[34];
  float* out = (float*)d_out;
  (void)in_sizes; (void)n_in;

  // ---- workspace layout (aliased; padded activations; 194,810,112 B) ----
  const size_t NEEDED = 194810112ull;
  if (ws_size < NEEDED) {
    zero_out_k<<<(out_size + 255) / 256, 256, 0, stream>>>(out, out_size);
    return;
  }
  char* base = (char*)d_ws;
  size_t off = 0;
  auto alloc = [&](size_t bytes) -> char* {
    char* p = base + off;
    off += (bytes + 255) & ~(size_t)255;
    return p;
  };
  _Float16* W2t = (_Float16*)alloc(409600);     // 25*128*64*2
  _Float16* W3t = (_Float16*)alloc(1638400);    // 25*256*128*2
  _Float16* W4t = (_Float16*)alloc(6553600);    // 25*512*256*2
  _Float16* W5t = (_Float16*)alloc(13107200);   // 25*512*512*2
  _Float16* W6t = (_Float16*)alloc(26214400);   // 25*512*1024*2
  _Float16* W7t = (_Float16*)alloc(9830400);    // 25*256*768*2
  _Float16* W8t = (_Float16*)alloc(57600);      // 48*25*24 fp16
  char* Rbig = alloc(72466432);   // c1(67.1M) | cat7(53.5M)+cat6(18.9M) | up7(67.1M)
  char* c2b_ = alloc(33554432);   // c2 (2,256,256,128) unpadded
  char* R1 = alloc(17305600);     // p1(17.3M) | c6(8.4M) | c7(16.8M) | c8(1M)
  char* R2 = alloc(13672448);     // p2(8.9M) ; [p3(4.7M) | p4(2.65M)+c5(2.1M)]

  _Float16* c1 = (_Float16*)Rbig;                    // (2,512,512,64) unpadded
  _Float16* cat7 = (_Float16*)Rbig;                  // (2,132,132,768) padded
  _Float16* cat6 = (_Float16*)(Rbig + 53526528);     // (2,68,68,1024) padded
  _Float16* up7b = (_Float16*)Rbig;                  // (2,256,256,256) unpadded
  _Float16* c2buf = (_Float16*)c2b_;                 // (2,256,256,128) unpadded
  _Float16* p1 = (_Float16*)R1;                      // (2,260,260,64) padded
  _Float16* c6 = (_Float16*)R1;                      // (2,64,64,512) unpadded
  _Float16* c7 = (_Float16*)R1;                      // (2,128,128,256) unpadded
  _Float16* c8 = (_Float16*)R1;                      // (2,256,256,4) unpadded
  _Float16* p2 = (_Float16*)R2;                      // (2,132,132,128) padded
  _Float16* p3 = (_Float16*)(R2 + 8921088);          // (2,68,68,256) padded
  _Float16* p4 = (_Float16*)(R2 + 8921088);          // (2,36,36,512) padded (aliases p3!)
  _Float16* c5 = (_Float16*)(R2 + 8921088 + 2654208);// (2,32,32,512) unpadded

  // zero halo buffers not aliased with earlier-live data.
  // NOTE: p4 aliases p3, so p4's halo must be zeroed AFTER conv4 (p3 dead).
  zero16_k<<<(1081600 + 255) / 256, 256, 0, stream>>>(p1, 1081600);   // 17.3MB
  zero16_k<<<(557568 + 255) / 256, 256, 0, stream>>>(p2, 557568);     // 8.9MB
  zero16_k<<<(295936 + 255) / 256, 256, 0, stream>>>(p3, 295936);     // 4.7MB

  // weight transforms (fold BN scale into weights)
  wtrans16<<<(25 * 128 * 64 + 255) / 256, 256, 0, stream>>>(w[2], W2t, gg[2], 128, 64, 25 * 128 * 64);
  wtrans16<<<(25 * 256 * 128 + 255) / 256, 256, 0, stream>>>(w[3], W3t, gg[3], 256, 128, 25 * 256 * 128);
  wtrans16<<<(25 * 512 * 256 + 255) / 256, 256, 0, stream>>>(w[4], W4t, gg[4], 512, 256, 25 * 512 * 256);
  wtrans16<<<(25 * 512 * 512 + 255) / 256, 256, 0, stream>>>(w[5], W5t, gg[5], 512, 512, 25 * 512 * 512);
  wtrans16<<<(25 * 512 * 1024 + 255) / 256, 256, 0, stream>>>(w[6], W6t, gg[6], 512, 1024, 25 * 512 * 1024);
  wtrans16<<<(25 * 256 * 768 + 255) / 256, 256, 0, stream>>>(w[7], W7t, gg[7], 256, 768, 25 * 256 * 768);
  wtrans8<<<(28800 + 255) / 256, 256, 0, stream>>>(w[8], W8t, gg[8]);

  conv1_k<<<2048, 256, 0, stream>>>(data, w[1], gg[1], bb[1], ee[1], c1);
  pool_k<<<1048576 / 256, 256, 0, stream>>>(c1, p1, 64, 64, 512, 262144, 0,
                                            260, 67600, 522, 8, 8, 3, 1048576);
  // c1 dead -> zero cat7/cat6 (they alias c1's region)
  zero16_k<<<(3345408 + 255) / 256, 256, 0, stream>>>(cat7, 3345408);  // 53.5MB
  zero16_k<<<(1183744 + 255) / 256, 256, 0, stream>>>(cat6, 1183744);  // 18.9MB

  conv_gemm<4, 4, 1><<<dim3(1024, 1), 256, 0, stream>>>(p1, W2t, gg[2], bb[2], ee[2], c2buf,
      64, 128, 8, 8, 64, 260, 67600, 522, 128, 0, 256, 65536, 0);
  pool_k<<<524288 / 256, 256, 0, stream>>>(c2buf, p2, 128, 128, 256, 65536, 0,
                                           132, 17424, 266, 7, 7, 4, 524288);
  conv_gemm<4, 4, 2><<<dim3(256, 2), 256, 0, stream>>>(p2, W3t, gg[3], bb[3], ee[3], cat7,
      128, 256, 7, 7, 128, 132, 17424, 266, 768, 0, 132, 17424, 266);
  pool_k<<<262144 / 256, 256, 0, stream>>>(cat7, p3, 768, 256, 132, 17424, 266,
                                           68, 4624, 138, 6, 6, 5, 262144);
  conv_gemm<4, 4, 2><<<dim3(64, 4), 256, 0, stream>>>(p3, W4t, gg[4], bb[4], ee[4], cat6,
      256, 512, 6, 6, 256, 68, 4624, 138, 1024, 0, 68, 4624, 138);
  // p3 dead -> now safe to zero p4's halo (p4 aliases p3's bytes)
  zero16_k<<<(165888 + 255) / 256, 256, 0, stream>>>(p4, 165888);      // 2.65MB
  pool_k<<<131072 / 256, 256, 0, stream>>>(cat6, p4, 1024, 512, 68, 4624, 138,
                                           36, 1296, 74, 5, 5, 6, 131072);
  conv_gemm<2, 2, 2><<<dim3(32, 8), 256, 0, stream>>>(p4, W5t, gg[5], bb[5], ee[5], c5,
      512, 512, 5, 5, 512, 36, 1296, 74, 512, 0, 32, 1024, 0);
  up_k<<<524288 / 256, 256, 0, stream>>>(c5, cat6, 512, 1024, 512,
                                         32, 1024, 0, 68, 4624, 138,
                                         5, 5, 6, 31.f / 63.f, 524288);
  conv_gemm<4, 4, 2><<<dim3(64, 4), 256, 0, stream>>>(cat6, W6t, gg[6], bb[6], ee[6], c6,
      1024, 512, 6, 6, 1024, 68, 4624, 138, 512, 0, 64, 4096, 0);
  up_k<<<2097152 / 256, 256, 0, stream>>>(c6, cat7, 512, 768, 256,
                                          64, 4096, 0, 132, 17424, 266,
                                          6, 6, 6, 63.f / 127.f, 2097152);
  conv_gemm<4, 4, 2><<<dim3(256, 2), 256, 0, stream>>>(cat7, W7t, gg[7], bb[7], ee[7], c7,
      768, 256, 7, 7, 768, 132, 17424, 266, 256, 0, 128, 16384, 0);
  up_k<<<4194304 / 256, 256, 0, stream>>>(c7, up7b, 256, 256, 0,
                                          128, 16384, 0, 256, 65536, 0,
                                          7, 7, 5, 127.f / 255.f, 4194304);
  conv8_lds<<<512, 256, 0, stream>>>(c2buf, up7b, W8t, bb[8], gg[8], ee[8], c8);
  final_k<<<524288 / 256, 256, 0, stream>>>(data, c8, wo, bo, out);
}

// Round 10
// 1804.338 us; speedup vs baseline: 1.1428x; 1.0748x over previous
//
#include <hip/hip_runtime.h>
#include <hip/hip_bf16.h>

typedef _Float16 f16x8 __attribute__((ext_vector_type(8)));
typedef _Float16 f16x4 __attribute__((ext_vector_type(4)));
typedef float f32x4 __attribute__((ext_vector_type(4)));

#define BN_S 0.99999500003749975f  // 1/sqrt(1+1e-5)

__device__ inline f16x8 f16x8_zero() {
  f16x8 v = {(_Float16)0.f, (_Float16)0.f, (_Float16)0.f, (_Float16)0.f,
             (_Float16)0.f, (_Float16)0.f, (_Float16)0.f, (_Float16)0.f};
  return v;
}

__device__ __forceinline__ void load_lds16(const _Float16* g, _Float16* l) {
  __builtin_amdgcn_global_load_lds(
      (const __attribute__((address_space(1))) void*)g,
      (__attribute__((address_space(3))) void*)l, 16, 0, 0);
}

__global__ void zero_out_k(float* __restrict__ out, int n) {
  const int idx = blockIdx.x * 256 + threadIdx.x;
  if (idx < n) out[idx] = 0.f;
}

// zero n16 16-byte blocks
__global__ void zero16_k(_Float16* __restrict__ p, int n16) {
  const int idx = blockIdx.x * 256 + threadIdx.x;
  if (idx < n16) ((f16x8*)p)[idx] = f16x8_zero();
}

// ---------------------------------------------------------------------------
// Weight transform: OIHW fp32 -> [25][O][C] fp16, pre-scaled by g*BN_S.
// ---------------------------------------------------------------------------
__global__ void wtrans16(const float* __restrict__ src, _Float16* __restrict__ dst,
                         const float* __restrict__ g, int O, int C, int total) {
  const int idx = blockIdx.x * 256 + threadIdx.x;  // (t, o, c)
  if (idx >= total) return;
  const int OC = O * C;
  const int t = idx / OC;
  const int rem = idx - t * OC;
  const int o = rem / C;
  const int c = rem - o * C;
  dst[idx] = (_Float16)(src[(size_t)(o * C + c) * 25 + t] * g[o] * BN_S);
}

// conv8 weights: OIHW fp32 (O=3,C=384) -> [48 chunks][25 taps][3][8] fp16.
__global__ void wtrans8(const float* __restrict__ src, _Float16* __restrict__ dst,
                        const float* __restrict__ g) {
  const int idx = blockIdx.x * 256 + threadIdx.x;
  if (idx >= 28800) return;
  const int c = idx / 600;
  const int r = idx - c * 600;
  const int tap = r / 24;
  const int q = r - tap * 24;
  const int o = q >> 3, j = q & 7;
  const int cin = (c < 16) ? (c * 8 + j) : (128 + (c - 16) * 8 + j);
  dst[idx] = (_Float16)(src[((size_t)o * 384 + cin) * 25 + tap] * g[o] * BN_S);
}

// ---------------------------------------------------------------------------
// Implicit-GEMM 5x5 conv + BN + ReLU.  Cin%(32*KS)==0, Cout%BM==0, px%BN==0.
// Block tile BM(cout) x BN(px); 4 waves 2x2; KS k-steps staged per barrier
// into double-buffered LDS via global_load_lds(16B). XOR-swizzled LDS.
// TAG gives each layer a distinct symbol for profiling.
// Tile-shrink rule (r5/r9 lesson): shrink BM (re-reads small activation
// panel), never BN (re-reads large weight panel -> 6x FETCH blowup).
// ---------------------------------------------------------------------------
template <int MF, int NF, int KS, int TAG>
__global__ __launch_bounds__(256) void conv_gemm(
    const _Float16* __restrict__ in, const _Float16* __restrict__ wt,
    const float* __restrict__ gg, const float* __restrict__ bbv,
    const float* __restrict__ ev, _Float16* __restrict__ out,
    int Cin, int Cout, int lw, int lh,
    int inS, int Wpi, int bsi, int ibase,
    int outS, int outOff, int Wpo, int bso, int obase) {
  constexpr int BM = MF * 32;
  constexpr int BN = NF * 32;
  constexpr int SUB_A = BM * 32;  // halfwords per k-substep
  constexpr int SUB_B = BN * 32;
  __shared__ _Float16 sA[2][SUB_A * KS];
  __shared__ _Float16 sB[2][SUB_B * KS];

  const int tid = threadIdx.x;
  const int lane = tid & 63;
  const int wid = tid >> 6;
  const int wm = wid >> 1, wn = wid & 1;
  const int lr = lane >> 4, lc = lane & 15;
  const int n0 = blockIdx.x * BN;
  const int m0 = blockIdx.y * BM;
  const int H = 1 << lh, W = 1 << lw;
  const int nkb = Cin >> 5;

  // staging identity: linear g = issue*256 + tid; row=g>>2, slot=g&3
  const int r0 = tid >> 2;
  const int chunk = (tid & 3) ^ ((r0 >> 1) & 3);  // same for row r0+64

  const _Float16* a0 = wt + (size_t)(m0 + r0) * Cin + (chunk << 3);
  const _Float16* a1 = a0 + ((size_t)Cin << 6);  // used only if BM==128
  const int t0off = -2 * Wpi - 2;  // tap (dy=0,dx=0)
  const _Float16 *b0, *b1 = nullptr;
  {
    int n = n0 + r0;
    int pix0 = (n >> (lw + lh)) * bsi + ((n >> lw) & (H - 1)) * Wpi + (n & (W - 1)) + ibase;
    b0 = in + (size_t)(pix0 + t0off) * inS + (chunk << 3);
    if constexpr (BN == 128) {
      n = n0 + r0 + 64;
      int pix1 = (n >> (lw + lh)) * bsi + ((n >> lw) & (H - 1)) * Wpi + (n & (W - 1)) + ibase;
      b1 = in + (size_t)(pix1 + t0off) * inS + (chunk << 3);
    }
  }

  // ds_read fragment swizzle (halfwords)
  const int swz = (lr ^ ((lc >> 1) & 3)) << 3;

  f32x4 acc[MF][NF];
  const f32x4 vz = {0.f, 0.f, 0.f, 0.f};
#pragma unroll
  for (int i = 0; i < MF; ++i)
#pragma unroll
    for (int j = 0; j < NF; ++j) acc[i][j] = vz;

  const int np = 25 * nkb / KS;  // staged groups
  int kb = 0, dx = 0;
  const size_t a_tap = (size_t)Cout * Cin - ((size_t)nkb << 5);
  const int woff = wid << 9;  // wave LDS base within a 4KB issue (halfwords)

  // advance staging pointers by one group (KS k-steps)
  auto advance = [&]() {
    a0 += 32 * KS; b0 += 32 * KS;
    if constexpr (BM == 128) a1 += 32 * KS;
    if constexpr (BN == 128) b1 += 32 * KS;
    kb += KS;
    if (kb == nkb) {
      kb = 0;
      a0 += a_tap;
      if constexpr (BM == 128) a1 += a_tap;
      int pd;
      if (++dx == 5) { dx = 0; pd = Wpi - 4; } else pd = 1;
      const ptrdiff_t bd = (ptrdiff_t)pd * inS - ((ptrdiff_t)nkb << 5);
      b0 += bd;
      if constexpr (BN == 128) b1 += bd;
    }
  };
  auto stage = [&](int buf) {
#pragma unroll
    for (int s = 0; s < KS; ++s) {
      _Float16* sa = sA[buf] + s * SUB_A + woff;
      _Float16* sb = sB[buf] + s * SUB_B + woff;
      load_lds16(a0 + 32 * s, sa);
      if constexpr (BM == 128) load_lds16(a1 + 32 * s, sa + 2048);
      load_lds16(b0 + 32 * s, sb);
      if constexpr (BN == 128) load_lds16(b1 + 32 * s, sb + 2048);
    }
  };

  // prologue: stage group 0 into buf 0
  stage(0);
  __syncthreads();

  int cur = 0;
  for (int t = 0; t < np; ++t) {
    if (t + 1 < np) {
      advance();
      stage(cur ^ 1);
    }
    const _Float16* pA = sA[cur];
    const _Float16* pB = sB[cur];
#pragma unroll
    for (int s = 0; s < KS; ++s) {
      f16x8 af[MF], bf[NF];
#pragma unroll
      for (int i = 0; i < MF; ++i)
        af[i] = *(const f16x8*)(pA + s * SUB_A + ((wm * (MF * 16) + (i << 4) + lc) << 5) + swz);
#pragma unroll
      for (int i = 0; i < NF; ++i)
        bf[i] = *(const f16x8*)(pB + s * SUB_B + ((wn * (NF * 16) + (i << 4) + lc) << 5) + swz);
#pragma unroll
      for (int mi = 0; mi < MF; ++mi)
#pragma unroll
        for (int ni = 0; ni < NF; ++ni)
          acc[mi][ni] =
              __builtin_amdgcn_mfma_f32_16x16x32_f16(af[mi], bf[ni], acc[mi][ni], 0, 0, 0);
    }
    __syncthreads();  // drains stage(cur^1) loads + fences buf reuse
    cur ^= 1;
  }

  // Epilogue: D col = lane&15 -> pixel, row = lr*4+j -> cout
#pragma unroll
  for (int mi = 0; mi < MF; ++mi) {
    const int ob = m0 + wm * (MF * 16) + (mi << 4) + (lr << 2);
    const f32x4 gv = *(const f32x4*)(gg + ob);
    const f32x4 bv = *(const f32x4*)(bbv + ob);
    const f32x4 evv = *(const f32x4*)(ev + ob);
#pragma unroll
    for (int ni = 0; ni < NF; ++ni) {
      const int n = n0 + wn * (NF * 16) + (ni << 4) + lc;
      const int y = (n >> lw) & (H - 1);
      const int x = n & (W - 1);
      const int bb_ = n >> (lw + lh);
      const size_t op = (size_t)(bb_ * bso + y * Wpo + x + obase) * outS + outOff + ob;
      f16x4 h;
#pragma unroll
      for (int j = 0; j < 4; ++j) {
        const float s = gv[j] * BN_S;
        float v = acc[mi][ni][j] + (bv[j] * s + evv[j]);
        v = v > 0.f ? v : 0.f;
        h[j] = (_Float16)v;
      }
      *(f16x4*)(out + op) = h;
    }
  }
}

// ---------------------------------------------------------------------------
// conv1: Cin=3, Cout=64, 512x512, fp32 NCHW data + raw fp32 weights.
// ---------------------------------------------------------------------------
__global__ __launch_bounds__(256) void conv1_k(
    const float* __restrict__ data, const float* __restrict__ w1,
    const float* __restrict__ g1, const float* __restrict__ b1,
    const float* __restrict__ e1, _Float16* __restrict__ out) {
  __shared__ float patch[3][20][20];
  const int tid = threadIdx.x;
  const int bid = blockIdx.x;
  const int tx = bid & 31, ty = (bid >> 5) & 31, b = bid >> 10;

  for (int i = tid; i < 1200; i += 256) {
    const int c = i / 400;
    const int r = i - c * 400;
    const int pyy = r / 20;
    const int pxx = r - pyy * 20;
    const int gy = (ty << 4) + pyy - 2, gx = (tx << 4) + pxx - 2;
    float v = 0.f;
    if ((unsigned)gy < 512u && (unsigned)gx < 512u)
      v = data[((size_t)(b * 3 + c) << 18) + (gy << 9) + gx];
    patch[c][pyy][pxx] = v;
  }
  __syncthreads();

  const int py = tid >> 4, px = tid & 15;
  float acc[64];
#pragma unroll
  for (int o = 0; o < 64; ++o) acc[o] = 0.f;

  for (int c = 0; c < 3; ++c)
    for (int dy = 0; dy < 5; ++dy) {
#pragma unroll
      for (int dx = 0; dx < 5; ++dx) {
        const float v = patch[c][py + dy][px + dx];
        const float* wb = w1 + c * 25 + dy * 5 + dx;
#pragma unroll
        for (int o = 0; o < 64; ++o) acc[o] = fmaf(v, wb[o * 75], acc[o]);
      }
    }

  const int y = (ty << 4) + py, x = (tx << 4) + px;
  _Float16* op = out + ((size_t)(((b << 9) + y) << 9) + x) * 64;
#pragma unroll
  for (int oc = 0; oc < 8; ++oc) {
    f16x8 h;
#pragma unroll
    for (int j = 0; j < 8; ++j) {
      const int o = (oc << 3) + j;
      const float s = g1[o] * BN_S;
      const float t = b1[o] * s + e1[o];
      float v = fmaf(acc[o], s, t);
      v = v > 0.f ? v : 0.f;
      h[j] = (_Float16)v;
    }
    *(f16x8*)(op + (oc << 3)) = h;
  }
}

// ---------------------------------------------------------------------------
// avg-pool 2x2 stride 2, NHWC fp16, generic padded/unpadded addressing
// ---------------------------------------------------------------------------
__global__ void pool_k(const _Float16* __restrict__ in, _Float16* __restrict__ out,
                       int inS, int outS, int Wpi, int bsi, int ibase,
                       int Wpo, int bso, int obase,
                       int lwo, int lho, int lcc, int total) {
  const int idx = blockIdx.x * 256 + threadIdx.x;
  if (idx >= total) return;
  const int cc = idx & ((1 << lcc) - 1);
  const int pix = idx >> lcc;
  const int x = pix & ((1 << lwo) - 1);
  const int y = (pix >> lwo) & ((1 << lho) - 1);
  const int b = pix >> (lwo + lho);
  const int ip = b * bsi + (y << 1) * Wpi + (x << 1) + ibase;
  const _Float16* p = in + (size_t)ip * inS + (cc << 3);
  const f16x8 v00 = *(const f16x8*)p;
  const f16x8 v01 = *(const f16x8*)(p + inS);
  const f16x8 v10 = *(const f16x8*)(p + (size_t)Wpi * inS);
  const f16x8 v11 = *(const f16x8*)(p + (size_t)(Wpi + 1) * inS);
  f16x8 r;
#pragma unroll
  for (int j = 0; j < 8; ++j)
    r[j] = (_Float16)(((float)v00[j] + (float)v01[j] + (float)v10[j] + (float)v11[j]) * 0.25f);
  const int op = b * bso + y * Wpo + x + obase;
  *(f16x8*)(out + (size_t)op * outS + (cc << 3)) = r;
}

// ---------------------------------------------------------------------------
// bilinear 2x upsample (align_corners=True), NHWC fp16
// ---------------------------------------------------------------------------
__global__ void up_k(const _Float16* __restrict__ in, _Float16* __restrict__ out,
                     int inS, int outS, int outOff,
                     int Wpi, int bsi, int ibase,
                     int Wpo, int bso, int obase,
                     int lwi, int lhi, int lcc, float scale, int total) {
  const int idx = blockIdx.x * 256 + threadIdx.x;
  if (idx >= total) return;
  const int cc = idx & ((1 << lcc) - 1);
  const int pix = idx >> lcc;
  const int lwo = lwi + 1, lho = lhi + 1;
  const int ox = pix & ((1 << lwo) - 1);
  const int oy = (pix >> lwo) & ((1 << lho) - 1);
  const int b = pix >> (lwo + lho);
  const int Hi = 1 << lhi, Wi = 1 << lwi;
  const float fy = oy * scale;
  const int y0 = (int)fy;
  const float wy = fy - y0;
  const int y1 = min(y0 + 1, Hi - 1);
  const float fx = ox * scale;
  const int x0 = (int)fx;
  const float wx = fx - x0;
  const int x1 = min(x0 + 1, Wi - 1);
  const int rbase = b * bsi + ibase;
  const _Float16* basep = in + (cc << 3);
  const f16x8 v00 = *(const f16x8*)(basep + (size_t)(rbase + y0 * Wpi + x0) * inS);
  const f16x8 v01 = *(const f16x8*)(basep + (size_t)(rbase + y0 * Wpi + x1) * inS);
  const f16x8 v10 = *(const f16x8*)(basep + (size_t)(rbase + y1 * Wpi + x0) * inS);
  const f16x8 v11 = *(const f16x8*)(basep + (size_t)(rbase + y1 * Wpi + x1) * inS);
  f16x8 r;
#pragma unroll
  for (int j = 0; j < 8; ++j) {
    const float top = (float)v00[j] * (1.f - wx) + (float)v01[j] * wx;
    const float bot = (float)v10[j] * (1.f - wx) + (float)v11[j] * wx;
    r[j] = (_Float16)(top * (1.f - wy) + bot * wy);
  }
  const int op = b * bso + oy * Wpo + ox + obase;
  *(f16x8*)(out + (size_t)op * outS + outOff + (cc << 3)) = r;
}

// ---------------------------------------------------------------------------
// conv8 (LDS-tiled): Cin=384 (= c2[128ch] ++ up7[256ch]), Cout=3, 256x256.
// ---------------------------------------------------------------------------
__global__ __launch_bounds__(256) void conv8_lds(
    const _Float16* __restrict__ inA, const _Float16* __restrict__ inB,
    const _Float16* __restrict__ wt, const float* __restrict__ b8,
    const float* __restrict__ g8, const float* __restrict__ e8,
    _Float16* __restrict__ out) {
  __shared__ f16x8 patch[2][20][20];
  const int tid = threadIdx.x;
  const int bid = blockIdx.x;  // 512
  const int tx = bid & 15, ty = (bid >> 4) & 15, b = bid >> 8;
  const int px = tid & 15, py = tid >> 4;
  const int x0 = tx << 4, y0 = ty << 4;

  float a0 = 0.f, a1 = 0.f, a2 = 0.f;
  for (int c = 0; c < 48; ++c) {
    const _Float16* sbase;
    int str;
    if (c < 16) { sbase = inA + ((size_t)b << 23) + (c << 3); str = 128; }
    else        { sbase = inB + ((size_t)b << 24) + ((c - 16) << 3); str = 256; }
    for (int i = tid; i < 400; i += 256) {
      const int pyy = i / 20, pxx = i - pyy * 20;
      const int gy = y0 + pyy - 2, gx = x0 + pxx - 2;
      f16x8 v = f16x8_zero();
      if ((unsigned)gy < 256u && (unsigned)gx < 256u)
        v = *(const f16x8*)(sbase + (size_t)((gy << 8) + gx) * str);
      patch[c & 1][pyy][pxx] = v;
    }
    __syncthreads();
    const _Float16* wb_c = wt + c * 600;
#pragma unroll
    for (int dy = 0; dy < 5; ++dy) {
#pragma unroll
      for (int dxx = 0; dxx < 5; ++dxx) {
        const f16x8 v = patch[c & 1][py + dy][px + dxx];
        const _Float16* wb = wb_c + (dy * 5 + dxx) * 24;
#pragma unroll
        for (int j = 0; j < 8; ++j) {
          const float f = (float)v[j];
          a0 = fmaf(f, (float)wb[j], a0);
          a1 = fmaf(f, (float)wb[8 + j], a1);
          a2 = fmaf(f, (float)wb[16 + j], a2);
        }
      }
    }
  }

  const float s0 = g8[0] * BN_S, t0 = b8[0] * s0 + e8[0];
  const float s1 = g8[1] * BN_S, t1 = b8[1] * s1 + e8[1];
  const float s2 = g8[2] * BN_S, t2 = b8[2] * s2 + e8[2];
  float r0 = a0 + t0, r1 = a1 + t1, r2 = a2 + t2;
  r0 = r0 > 0.f ? r0 : 0.f;
  r1 = r1 > 0.f ? r1 : 0.f;
  r2 = r2 > 0.f ? r2 : 0.f;
  f16x4 h;
  h[0] = (_Float16)r0; h[1] = (_Float16)r1; h[2] = (_Float16)r2; h[3] = (_Float16)0.f;
  const int opix = (b << 16) + ((y0 + py) << 8) + (x0 + px);
  *(f16x4*)(out + (size_t)opix * 4) = h;
}

// ---------------------------------------------------------------------------
// final: bilinear up(c8, 256->512) + 1x1 conv (wo,bo) + out = data*core (fp32)
// ---------------------------------------------------------------------------
__global__ void final_k(const float* __restrict__ data, const _Float16* __restrict__ c8,
                        const float* __restrict__ wo, const float* __restrict__ bo,
                        float* __restrict__ out) {
  const int idx = blockIdx.x * 256 + threadIdx.x;  // < 524288
  const int x = idx & 511, y = (idx >> 9) & 511, b = idx >> 18;
  const float sc = 255.f / 511.f;
  const float fy = y * sc;
  const int y0 = (int)fy;
  const float wy = fy - y0;
  const int y1 = min(y0 + 1, 255);
  const float fx = x * sc;
  const int x0 = (int)fx;
  const float wx = fx - x0;
  const int x1 = min(x0 + 1, 255);
  const f16x4 v00 = *(const f16x4*)(c8 + (size_t)((((b << 8) + y0) << 8) + x0) * 4);
  const f16x4 v01 = *(const f16x4*)(c8 + (size_t)((((b << 8) + y0) << 8) + x1) * 4);
  const f16x4 v10 = *(const f16x4*)(c8 + (size_t)((((b << 8) + y1) << 8) + x0) * 4);
  const f16x4 v11 = *(const f16x4*)(c8 + (size_t)((((b << 8) + y1) << 8) + x1) * 4);
  float u[3];
#pragma unroll
  for (int j = 0; j < 3; ++j) {
    const float top = (float)v00[j] * (1.f - wx) + (float)v01[j] * wx;
    const float bot = (float)v10[j] * (1.f - wx) + (float)v11[j] * wx;
    u[j] = top * (1.f - wy) + bot * wy;
  }
#pragma unroll
  for (int c = 0; c < 3; ++c) {
    const float core = bo[c] + wo[c * 3 + 0] * u[0] + wo[c * 3 + 1] * u[1] + wo[c * 3 + 2] * u[2];
    const size_t oi = ((size_t)(b * 3 + c) << 18) + (y << 9) + x;
    out[oi] = data[oi] * core;
  }
}

// ---------------------------------------------------------------------------
extern "C" void kernel_launch(void* const* d_in, const int* in_sizes, int n_in,
                              void* d_out, int out_size, void* d_ws, size_t ws_size,
                              hipStream_t stream) {
  const float* data = (const float*)d_in[0];
  const float *w[9], *bb[9], *gg[9], *ee[9];
  for (int n = 1; n <= 8; ++n) {
    w[n] = (const float*)d_in[1 + (n - 1) * 4];
    bb[n] = (const float*)d_in[2 + (n - 1) * 4];
    gg[n] = (const float*)d_in[3 + (n - 1) * 4];
    ee[n] = (const float*)d_in[4 + (n - 1) * 4];
  }
  const float* wo = (const float*)d_in[33];
  const float* bo = (const float*)d_in[34];
  float* out = (float*)d_out;
  (void)in_sizes; (void)n_in;

  // ---- workspace layout (aliased; padded activations; 194,810,112 B) ----
  // LIVENESS NOTE (r9 lesson): cat7's c3-half is live conv3 -> conv7 (skip
  // connection); the cat7 region must NOT be reused between those points.
  const size_t NEEDED = 194810112ull;
  if (ws_size < NEEDED) {
    zero_out_k<<<(out_size + 255) / 256, 256, 0, stream>>>(out, out_size);
    return;
  }
  char* base = (char*)d_ws;
  size_t off = 0;
  auto alloc = [&](size_t bytes) -> char* {
    char* p = base + off;
    off += (bytes + 255) & ~(size_t)255;
    return p;
  };
  _Float16* W2t = (_Float16*)alloc(409600);     // 25*128*64*2
  _Float16* W3t = (_Float16*)alloc(1638400);    // 25*256*128*2
  _Float16* W4t = (_Float16*)alloc(6553600);    // 25*512*256*2
  _Float16* W5t = (_Float16*)alloc(13107200);   // 25*512*512*2
  _Float16* W6t = (_Float16*)alloc(26214400);   // 25*512*1024*2
  _Float16* W7t = (_Float16*)alloc(9830400);    // 25*256*768*2
  _Float16* W8t = (_Float16*)alloc(57600);      // 48*25*24 fp16
  char* Rbig = alloc(72466432);   // c1(67.1M) | cat7(53.5M)+cat6(18.9M) | up7(67.1M)
  char* c2b_ = alloc(33554432);   // c2 (2,256,256,128) unpadded
  char* R1 = alloc(17305600);     // p1(17.3M) | c6(8.4M) | c7(16.8M) | c8(1M)
  char* R2 = alloc(13672448);     // p2(8.9M) ; [p3(4.7M) | p4(2.65M)+c5(2.1M)]

  _Float16* c1 = (_Float16*)Rbig;                    // (2,512,512,64) unpadded
  _Float16* cat7 = (_Float16*)Rbig;                  // (2,132,132,768) padded
  _Float16* cat6 = (_Float16*)(Rbig + 53526528);     // (2,68,68,1024) padded
  _Float16* up7b = (_Float16*)Rbig;                  // (2,256,256,256) unpadded
  _Float16* c2buf = (_Float16*)c2b_;                 // (2,256,256,128) unpadded
  _Float16* p1 = (_Float16*)R1;                      // (2,260,260,64) padded
  _Float16* c6 = (_Float16*)R1;                      // (2,64,64,512) unpadded
  _Float16* c7 = (_Float16*)R1;                      // (2,128,128,256) unpadded
  _Float16* c8 = (_Float16*)R1;                      // (2,256,256,4) unpadded
  _Float16* p2 = (_Float16*)R2;                      // (2,132,132,128) padded
  _Float16* p3 = (_Float16*)(R2 + 8921088);          // (2,68,68,256) padded
  _Float16* p4 = (_Float16*)(R2 + 8921088);          // (2,36,36,512) padded (aliases p3!)
  _Float16* c5 = (_Float16*)(R2 + 8921088 + 2654208);// (2,32,32,512) unpadded

  // zero halo buffers not aliased with earlier-live data.
  // NOTE: p4 aliases p3, so p4's halo must be zeroed AFTER conv4 (p3 dead).
  zero16_k<<<(1081600 + 255) / 256, 256, 0, stream>>>(p1, 1081600);   // 17.3MB
  zero16_k<<<(557568 + 255) / 256, 256, 0, stream>>>(p2, 557568);     // 8.9MB
  zero16_k<<<(295936 + 255) / 256, 256, 0, stream>>>(p3, 295936);     // 4.7MB

  // weight transforms (fold BN scale into weights)
  wtrans16<<<(25 * 128 * 64 + 255) / 256, 256, 0, stream>>>(w[2], W2t, gg[2], 128, 64, 25 * 128 * 64);
  wtrans16<<<(25 * 256 * 128 + 255) / 256, 256, 0, stream>>>(w[3], W3t, gg[3], 256, 128, 25 * 256 * 128);
  wtrans16<<<(25 * 512 * 256 + 255) / 256, 256, 0, stream>>>(w[4], W4t, gg[4], 512, 256, 25 * 512 * 256);
  wtrans16<<<(25 * 512 * 512 + 255) / 256, 256, 0, stream>>>(w[5], W5t, gg[5], 512, 512, 25 * 512 * 512);
  wtrans16<<<(25 * 512 * 1024 + 255) / 256, 256, 0, stream>>>(w[6], W6t, gg[6], 512, 1024, 25 * 512 * 1024);
  wtrans16<<<(25 * 256 * 768 + 255) / 256, 256, 0, stream>>>(w[7], W7t, gg[7], 256, 768, 25 * 256 * 768);
  wtrans8<<<(28800 + 255) / 256, 256, 0, stream>>>(w[8], W8t, gg[8]);

  conv1_k<<<2048, 256, 0, stream>>>(data, w[1], gg[1], bb[1], ee[1], c1);
  pool_k<<<1048576 / 256, 256, 0, stream>>>(c1, p1, 64, 64, 512, 262144, 0,
                                            260, 67600, 522, 8, 8, 3, 1048576);
  // c1 dead -> zero cat7/cat6 (they alias c1's region)
  zero16_k<<<(3345408 + 255) / 256, 256, 0, stream>>>(cat7, 3345408);  // 53.5MB
  zero16_k<<<(1183744 + 255) / 256, 256, 0, stream>>>(cat6, 1183744);  // 18.9MB

  conv_gemm<4, 4, 1, 2><<<dim3(1024, 1), 256, 0, stream>>>(p1, W2t, gg[2], bb[2], ee[2], c2buf,
      64, 128, 8, 8, 64, 260, 67600, 522, 128, 0, 256, 65536, 0);
  pool_k<<<524288 / 256, 256, 0, stream>>>(c2buf, p2, 128, 128, 256, 65536, 0,
                                           132, 17424, 266, 7, 7, 4, 524288);
  conv_gemm<4, 4, 2, 3><<<dim3(256, 2), 256, 0, stream>>>(p2, W3t, gg[3], bb[3], ee[3], cat7,
      128, 256, 7, 7, 128, 132, 17424, 266, 768, 0, 132, 17424, 266);
  pool_k<<<262144 / 256, 256, 0, stream>>>(cat7, p3, 768, 256, 132, 17424, 266,
                                           68, 4624, 138, 6, 6, 5, 262144);
  // conv4: BM=64 M-split -> 512 blocks (2/CU)
  conv_gemm<2, 4, 2, 4><<<dim3(64, 8), 256, 0, stream>>>(p3, W4t, gg[4], bb[4], ee[4], cat6,
      256, 512, 6, 6, 256, 68, 4624, 138, 1024, 0, 68, 4624, 138);
  // p3 dead -> now safe to zero p4's halo (p4 aliases p3's bytes)
  zero16_k<<<(165888 + 255) / 256, 256, 0, stream>>>(p4, 165888);      // 2.65MB
  pool_k<<<131072 / 256, 256, 0, stream>>>(cat6, p4, 1024, 512, 68, 4624, 138,
                                           36, 1296, 74, 5, 5, 6, 131072);
  conv_gemm<2, 2, 2, 5><<<dim3(32, 8), 256, 0, stream>>>(p4, W5t, gg[5], bb[5], ee[5], c5,
      512, 512, 5, 5, 512, 36, 1296, 74, 512, 0, 32, 1024, 0);
  up_k<<<524288 / 256, 256, 0, stream>>>(c5, cat6, 512, 1024, 512,
                                         32, 1024, 0, 68, 4624, 138,
                                         5, 5, 6, 31.f / 63.f, 524288);
  // conv6: BM=64 M-split -> 512 blocks (2/CU)
  conv_gemm<2, 4, 2, 6><<<dim3(64, 8), 256, 0, stream>>>(cat6, W6t, gg[6], bb[6], ee[6], c6,
      1024, 512, 6, 6, 1024, 68, 4624, 138, 512, 0, 64, 4096, 0);
  up_k<<<2097152 / 256, 256, 0, stream>>>(c6, cat7, 512, 768, 256,
                                          64, 4096, 0, 132, 17424, 266,
                                          6, 6, 6, 63.f / 127.f, 2097152);
  conv_gemm<4, 4, 2, 7><<<dim3(256, 2), 256, 0, stream>>>(cat7, W7t, gg[7], bb[7], ee[7], c7,
      768, 256, 7, 7, 768, 132, 17424, 266, 256, 0, 128, 16384, 0);
  up_k<<<4194304 / 256, 256, 0, stream>>>(c7, up7b, 256, 256, 0,
                                          128, 16384, 0, 256, 65536, 0,
                                          7, 7, 5, 127.f / 255.f, 4194304);
  conv8_lds<<<512, 256, 0, stream>>>(c2buf, up7b, W8t, bb[8], gg[8], ee[8], c8);
  final_k<<<524288 / 256, 256, 0, stream>>>(data, c8, wo, bo, out);
}